// Round 17
// baseline (183.931 us; speedup 1.0000x reference)
//
#include <hip/hip_runtime.h>

#define NN 50000
#define NE 1600000
#define NB 782         // buckets = ceil(NN/64)
#define BSH 6          // bucket = dst >> 6
#define BCAP 2560      // per-bucket capacity: mean 2046 + ~11 sigma

// workspace layout (units of 4B)
#define OFF_H1    0          // bf16 [NN][128] = 3.2M u   (h1s = h1 * dinv)
#define OFF_HW2   9600000    // bf16 [NN][32]  = 0.8M u   (hw2s = hw2 * dinv)
#define OFF_H2    10400000   // f32  [NN][32]  = 1.6M u   (h2 = agg2+self+b2)
#define OFF_DINV  12000000   // [NN] f32
#define OFF_ROWS  12050000   // [NN+1] int
#define OFF_GCNT  12101000   // [NB] int
#define OFF_CSRC  12102000   // int[NE] = 1.6M u
#define OFF_BIN   13702000   // packed uint[NB*BCAP] = 2.0M u (dead after k_binB;
                             //  w1t bf16[128][128] + w2c uint[32*70] alias head)
// total: ~15.7M u * 4B = 63 MB

typedef __attribute__((ext_vector_type(8))) short bf16x8;
typedef __attribute__((ext_vector_type(8))) unsigned short u16x8;
typedef __attribute__((ext_vector_type(4))) float f32x4;
typedef __attribute__((ext_vector_type(4))) unsigned u32x4;
typedef __attribute__((ext_vector_type(2))) unsigned u32x2;

__device__ __forceinline__ unsigned short f2b(float f) {
    unsigned u = __float_as_uint(f);
    u += 0x7fffu + ((u >> 16) & 1u);
    return (unsigned short)(u >> 16);
}
__device__ __forceinline__ float b2f(unsigned short h) {
    return __uint_as_float((unsigned)h << 16);
}
__device__ __forceinline__ float blo(unsigned u) { return __uint_as_float(u << 16); }
__device__ __forceinline__ float bhi(unsigned u) { return __uint_as_float(u & 0xffff0000u); }

// Pass A: bin edges into 782 dst-buckets. Edge record packed to 4B:
// src in bits [15:0] (NN<65536), in-bucket dst (d&63) in bits [21:16].
__global__ __launch_bounds__(256) void k_binA(const int* __restrict__ ei,
                                              int* __restrict__ gcount,
                                              unsigned* __restrict__ binned) {
    __shared__ int hist[NB];
    const int t = threadIdx.x;
    for (int i = t; i < NB; i += 256) hist[i] = 0;
    __syncthreads();
    const int e0 = blockIdx.x * (NE / 256);      // 6250 edges/block, exact
    const int e1 = e0 + (NE / 256);
    for (int e = e0 + t; e < e1; e += 256)
        atomicAdd(&hist[ei[NE + e] >> BSH], 1);
    __syncthreads();
    for (int i = t; i < NB; i += 256) {
        const int v = hist[i];
        hist[i] = atomicAdd(&gcount[i], v);      // becomes global cursor
    }
    __syncthreads();
    for (int e = e0 + t; e < e1; e += 256) {
        const int s = ei[e], d = ei[NE + e];
        const int b = d >> BSH;
        const int pos = atomicAdd(&hist[b], 1);
        binned[(size_t)b * BCAP + pos] = (unsigned)s | ((unsigned)(d & 63) << 16);
    }
}

// Pass B: one block per 64-node bucket (782 blocks, ~2K edges each).
// obase computed per-block (reduce gcount[0..b-1]) -- k_base kernel folded in.
__global__ __launch_bounds__(256) void k_binB(const int* __restrict__ gcount,
                                              const unsigned* __restrict__ binned,
                                              int* __restrict__ rows,
                                              float* __restrict__ dinv,
                                              int* __restrict__ csrc) {
    __shared__ int deg[64];
    __shared__ int ofs[64];
    __shared__ int scn[64];
    __shared__ int red[256];
    const int b = blockIdx.x, t = threadIdx.x;
    const int n0 = b << BSH;
    const int nloc = (NN - n0 < 64) ? (NN - n0) : 64;
    const int cnt = gcount[b];
    // obase = exclusive prefix of gcount over buckets < b
    int part = 0;
    for (int i = t; i < b; i += 256) part += gcount[i];
    red[t] = part;
    if (t < 64) deg[t] = 0;
    __syncthreads();
    #pragma unroll
    for (int o = 128; o > 0; o >>= 1) {
        if (t < o) red[t] += red[t + o];
        __syncthreads();
    }
    const int obase = red[0];
    const unsigned* eb = binned + (size_t)b * BCAP;
    for (int i = t; i < cnt; i += 256) atomicAdd(&deg[eb[i] >> 16], 1);
    __syncthreads();
    if (t < 64) scn[t] = deg[t];
    __syncthreads();
    #pragma unroll
    for (int o = 1; o < 64; o <<= 1) {
        const int x = (t >= o && t < 64) ? scn[t - o] : 0;
        __syncthreads();
        if (t < 64) scn[t] += x;
        __syncthreads();
    }
    if (t < 64) {
        const int ep = scn[t] - deg[t];
        ofs[t] = ep;
        if (t < nloc) {
            rows[n0 + t] = obase + ep;
            dinv[n0 + t] = rsqrtf((float)deg[t] + 1.0f);
        }
    }
    if (b == NB - 1 && t == 0) rows[NN] = NE;
    __syncthreads();
    for (int i = t; i < cnt; i += 256) {
        const unsigned r = eb[i];
        const int local = atomicAdd(&ofs[r >> 16], 1);
        csrc[obase + local] = (int)(r & 0xffffu);
    }
}

// W1[k][c] f32 -> w1t[c][k] bf16; W2 f32 -> transposed paired dwords with
// stride-70 padding: w2c[j*70 + k2] = bf16(W2[2k2][j]) | bf16(W2[2k2+1][j])<<16
// (contiguous in k2 per output channel j -> vectorized LDS reads in k_gf1)
__global__ __launch_bounds__(256) void k_wconv(const float* __restrict__ W1,
                                               const float* __restrict__ W2,
                                               unsigned short* __restrict__ w1t,
                                               unsigned* __restrict__ w2c) {
    const int t = threadIdx.x;
    if (blockIdx.x < 16) {
        const int id = blockIdx.x * 1024 + t;
        #pragma unroll
        for (int i = 0; i < 4; ++i) {
            const int e = id + 256 * i;          // coalesced read of W1
            const int k = e >> 7, c = e & 127;
            w1t[c * 128 + k] = f2b(W1[e]);
        }
    } else {
        #pragma unroll
        for (int i = 0; i < 8; ++i) {
            const int e = t + 256 * i;           // 2048 paired entries
            const int k2 = e >> 5, j = e & 31;
            const unsigned lo = f2b(W2[(2 * k2) * 32 + j]);
            const unsigned hi = f2b(W2[(2 * k2 + 1) * 32 + j]);
            w2c[j * 70 + k2] = lo | (hi << 16);
        }
    }
}

// MFMA GEMM: h1s[n][c] = dinv[n] * sum_k xT[n][k] * W1[k][c], bf16 out.
// LDS holds only the x tile; B-fragments stream from w1t in L2.
__global__ __launch_bounds__(256) void k_gemm1(const float* __restrict__ x,
                                               const unsigned short* __restrict__ w1t,
                                               const float* __restrict__ dinv,
                                               unsigned short* __restrict__ h1s) {
    __shared__ unsigned short lxs[64 * 136];   // x tile; reused as out tile
    const int t = threadIdx.x;
    const int gn0 = blockIdx.x * 64;
    {
        const int col = t & 63, kr = t >> 6;
        const int gn = gn0 + col;
        #pragma unroll
        for (int i = 0; i < 4; ++i) {
            const int k0 = kr * 32 + i * 8;
            u16x8 v;
            #pragma unroll
            for (int j = 0; j < 8; ++j) {
                const float xv = (gn < NN) ? x[(size_t)(k0 + j) * NN + gn] : 0.f;
                v[j] = f2b(xv);
            }
            *(u16x8*)&lxs[col * 136 + k0] = v;
        }
    }
    __syncthreads();
    const int w = t >> 6, l = t & 63;
    const int lr = l & 15, lg = l >> 4;      // lg = 0..3
    const unsigned short* pa = &lxs[(w * 16 + lr) * 136 + lg * 8];
    f32x4 acc[8];
    #pragma unroll
    for (int ct = 0; ct < 8; ++ct) acc[ct] = (f32x4){0.f, 0.f, 0.f, 0.f};
    #pragma unroll
    for (int ks = 0; ks < 4; ++ks) {
        const bf16x8 av = *(const bf16x8*)&pa[ks * 32];
        const unsigned short* pw = &w1t[lr * 128 + ks * 32 + lg * 8];
        const bf16x8 b0 = *(const bf16x8*)&pw[0 * 16 * 128];
        const bf16x8 b1 = *(const bf16x8*)&pw[1 * 16 * 128];
        const bf16x8 b2 = *(const bf16x8*)&pw[2 * 16 * 128];
        const bf16x8 b3 = *(const bf16x8*)&pw[3 * 16 * 128];
        const bf16x8 b4 = *(const bf16x8*)&pw[4 * 16 * 128];
        const bf16x8 b5 = *(const bf16x8*)&pw[5 * 16 * 128];
        const bf16x8 b6 = *(const bf16x8*)&pw[6 * 16 * 128];
        const bf16x8 b7 = *(const bf16x8*)&pw[7 * 16 * 128];
        acc[0] = __builtin_amdgcn_mfma_f32_16x16x32_bf16(av, b0, acc[0], 0, 0, 0);
        acc[1] = __builtin_amdgcn_mfma_f32_16x16x32_bf16(av, b1, acc[1], 0, 0, 0);
        acc[2] = __builtin_amdgcn_mfma_f32_16x16x32_bf16(av, b2, acc[2], 0, 0, 0);
        acc[3] = __builtin_amdgcn_mfma_f32_16x16x32_bf16(av, b3, acc[3], 0, 0, 0);
        acc[4] = __builtin_amdgcn_mfma_f32_16x16x32_bf16(av, b4, acc[4], 0, 0, 0);
        acc[5] = __builtin_amdgcn_mfma_f32_16x16x32_bf16(av, b5, acc[5], 0, 0, 0);
        acc[6] = __builtin_amdgcn_mfma_f32_16x16x32_bf16(av, b6, acc[6], 0, 0, 0);
        acc[7] = __builtin_amdgcn_mfma_f32_16x16x32_bf16(av, b7, acc[7], 0, 0, 0);
    }
    __syncthreads();                 // all lxs reads done; safe to overwrite
    // C/D layout: col = lane&15, row = (lane>>4)*4 + reg  [m89-verified]
    const int nl0 = w * 16 + lg * 4;
    const float4 dv = *(const float4*)&dinv[gn0 + nl0];   // may overread past NN
    const float dva[4] = {dv.x, dv.y, dv.z, dv.w};        // into rows[]: harmless
    #pragma unroll
    for (int ct = 0; ct < 8; ++ct) {
        const int c = ct * 16 + lr;
        #pragma unroll
        for (int r = 0; r < 4; ++r)
            lxs[(nl0 + r) * 136 + c] = f2b(acc[ct][r] * dva[r]);
    }
    __syncthreads();
    {
        const int row = t >> 2, cb = (t & 3) * 32;
        const int gn = gn0 + row;
        if (gn < NN) {
            #pragma unroll
            for (int i = 0; i < 4; ++i)
                *(u16x8*)&h1s[(size_t)gn * 128 + cb + i * 8] =
                    *(const u16x8*)&lxs[row * 136 + cb + i * 8];
        }
    }
}

// FUSED gather1+fuse1, wave-local epilogue with VECTORIZED LDS access:
// h1l read as 8x b128 broadcast (same addr all lanes, conflict-free);
// w2l read as 16x b64 from stride-70 rows (4-lane bank groups ~ 1.6x, cheap).
// Epilogue LDS clocks ~58/wave vs ~128 before -> frees issue slots for the
// gather's load stream (gf1 fetch rate was 2.94 vs 3.65 TB/s pure-gather).
__global__ __launch_bounds__(256) void k_gf1(const int* __restrict__ rows,
                                             const int* __restrict__ csrc,
                                             const float* __restrict__ dinv,
                                             const unsigned short* __restrict__ h1s,
                                             const float* __restrict__ b1,
                                             const unsigned* __restrict__ w2c,
                                             unsigned short* __restrict__ hw2s) {
    __shared__ unsigned w2l[32 * 70];          // 8.75KB padded transposed
    __shared__ unsigned h1l[4][64];            // 1KB (dword rows)
    const int t = threadIdx.x;
    #pragma unroll
    for (int i = 0; i < 9; ++i) {
        const int idx = t + 256 * i;
        if (idx < 32 * 70) w2l[idx] = w2c[idx];
    }
    __syncthreads();                           // only barrier in kernel
    const int wid = t >> 6, lane = t & 63;
    const int n = __builtin_amdgcn_readfirstlane(blockIdx.x * 4 + wid);
    if (n >= NN) return;
    const int beg = rows[n], end = rows[n + 1];
    float ax0 = 0.f, ay0 = 0.f, ax1 = 0.f, ay1 = 0.f;
    float ax2 = 0.f, ay2 = 0.f, ax3 = 0.f, ay3 = 0.f;
    int p = beg;
    for (; p + 16 <= end; p += 16) {
        const int s0 = csrc[p + 0], s1 = csrc[p + 1], s2 = csrc[p + 2], s3 = csrc[p + 3];
        const int s4 = csrc[p + 4], s5 = csrc[p + 5], s6 = csrc[p + 6], s7 = csrc[p + 7];
        const int s8 = csrc[p + 8], s9 = csrc[p + 9], sa = csrc[p + 10], sb = csrc[p + 11];
        const int sc = csrc[p + 12], sd = csrc[p + 13], se = csrc[p + 14], sf = csrc[p + 15];
        const unsigned u0 = *(const unsigned*)&h1s[(size_t)s0 * 128 + lane * 2];
        const unsigned u1 = *(const unsigned*)&h1s[(size_t)s1 * 128 + lane * 2];
        const unsigned u2 = *(const unsigned*)&h1s[(size_t)s2 * 128 + lane * 2];
        const unsigned u3 = *(const unsigned*)&h1s[(size_t)s3 * 128 + lane * 2];
        const unsigned u4 = *(const unsigned*)&h1s[(size_t)s4 * 128 + lane * 2];
        const unsigned u5 = *(const unsigned*)&h1s[(size_t)s5 * 128 + lane * 2];
        const unsigned u6 = *(const unsigned*)&h1s[(size_t)s6 * 128 + lane * 2];
        const unsigned u7 = *(const unsigned*)&h1s[(size_t)s7 * 128 + lane * 2];
        const unsigned u8 = *(const unsigned*)&h1s[(size_t)s8 * 128 + lane * 2];
        const unsigned u9 = *(const unsigned*)&h1s[(size_t)s9 * 128 + lane * 2];
        const unsigned ua = *(const unsigned*)&h1s[(size_t)sa * 128 + lane * 2];
        const unsigned ub = *(const unsigned*)&h1s[(size_t)sb * 128 + lane * 2];
        const unsigned uc = *(const unsigned*)&h1s[(size_t)sc * 128 + lane * 2];
        const unsigned ud = *(const unsigned*)&h1s[(size_t)sd * 128 + lane * 2];
        const unsigned ue = *(const unsigned*)&h1s[(size_t)se * 128 + lane * 2];
        const unsigned uf = *(const unsigned*)&h1s[(size_t)sf * 128 + lane * 2];
        ax0 += blo(u0); ay0 += bhi(u0);
        ax1 += blo(u1); ay1 += bhi(u1);
        ax2 += blo(u2); ay2 += bhi(u2);
        ax3 += blo(u3); ay3 += bhi(u3);
        ax0 += blo(u4); ay0 += bhi(u4);
        ax1 += blo(u5); ay1 += bhi(u5);
        ax2 += blo(u6); ay2 += bhi(u6);
        ax3 += blo(u7); ay3 += bhi(u7);
        ax0 += blo(u8); ay0 += bhi(u8);
        ax1 += blo(u9); ay1 += bhi(u9);
        ax2 += blo(ua); ay2 += bhi(ua);
        ax3 += blo(ub); ay3 += bhi(ub);
        ax0 += blo(uc); ay0 += bhi(uc);
        ax1 += blo(ud); ay1 += bhi(ud);
        ax2 += blo(ue); ay2 += bhi(ue);
        ax3 += blo(uf); ay3 += bhi(uf);
    }
    for (; p + 4 <= end; p += 4) {
        const int s0 = csrc[p + 0], s1 = csrc[p + 1], s2 = csrc[p + 2], s3 = csrc[p + 3];
        const unsigned u0 = *(const unsigned*)&h1s[(size_t)s0 * 128 + lane * 2];
        const unsigned u1 = *(const unsigned*)&h1s[(size_t)s1 * 128 + lane * 2];
        const unsigned u2 = *(const unsigned*)&h1s[(size_t)s2 * 128 + lane * 2];
        const unsigned u3 = *(const unsigned*)&h1s[(size_t)s3 * 128 + lane * 2];
        ax0 += blo(u0); ay0 += bhi(u0);
        ax1 += blo(u1); ay1 += bhi(u1);
        ax2 += blo(u2); ay2 += bhi(u2);
        ax3 += blo(u3); ay3 += bhi(u3);
    }
    for (; p < end; ++p) {
        const int s = csrc[p];
        const unsigned u0 = *(const unsigned*)&h1s[(size_t)s * 128 + lane * 2];
        ax0 += blo(u0); ay0 += bhi(u0);
    }
    const float dn = dinv[n];
    const float sx = ((ax0 + ax1) + (ax2 + ax3)) * dn;
    const float sy = ((ay0 + ay1) + (ay2 + ay3)) * dn;
    // self-loop + bias + relu (h1s*dinv = h1/deg)
    const unsigned su = *(const unsigned*)&h1s[(size_t)n * 128 + lane * 2];
    const float2 bb = *(const float2*)&b1[lane * 2];
    const float vx = fmaxf(fmaf(blo(su), dn, sx) + bb.x, 0.f);
    const float vy = fmaxf(fmaf(bhi(su), dn, sy) + bb.y, 0.f);
    h1l[wid][lane] = (unsigned)f2b(vx) | ((unsigned)f2b(vy) << 16);
    // wave-local epilogue: same wave wrote h1l[wid] -- no barrier needed
    const int j = lane & 31, half = lane >> 5;
    const unsigned* hp = &h1l[wid][half * 32];
    const unsigned* wp = &w2l[j * 70 + half * 32];
    float acc = 0.f;
    #pragma unroll
    for (int i = 0; i < 8; ++i) {
        const u32x4 h = *(const u32x4*)&hp[i * 4];
        const u32x2 w0 = *(const u32x2*)&wp[i * 4];
        const u32x2 w1 = *(const u32x2*)&wp[i * 4 + 2];
        acc = fmaf(blo(h.x), blo(w0.x), acc);
        acc = fmaf(bhi(h.x), bhi(w0.x), acc);
        acc = fmaf(blo(h.y), blo(w0.y), acc);
        acc = fmaf(bhi(h.y), bhi(w0.y), acc);
        acc = fmaf(blo(h.z), blo(w1.x), acc);
        acc = fmaf(bhi(h.z), bhi(w1.x), acc);
        acc = fmaf(blo(h.w), blo(w1.y), acc);
        acc = fmaf(bhi(h.w), bhi(w1.y), acc);
    }
    acc += __shfl_xor(acc, 32);
    if (lane < 32) hw2s[(size_t)n * 32 + j] = f2b(acc * dn);
}

// one wave per dst node; 4 lane-groups x 16 channel-pairs: lane loads a
// 4B uint (2 channels) per edge -> 4 VMEM instrs cover 16 edges/lines.
// Reduce across groups via shfl_xor(16,32); fused epilogue:
// h2[n][j] = dinv*sum_e hw2s[src][j] + hw2s[n][j]*dinv + b2[j]
__global__ __launch_bounds__(256) void k_gather2(const int* __restrict__ rows,
                                                 const int* __restrict__ csrc,
                                                 const float* __restrict__ dinv,
                                                 const unsigned short* __restrict__ hw2s,
                                                 const float* __restrict__ b2,
                                                 float* __restrict__ h2) {
    const int n = __builtin_amdgcn_readfirstlane((blockIdx.x * 256 + threadIdx.x) >> 6);
    const int lane = threadIdx.x & 63;
    const int g = lane >> 4;             // edge slot 0..3
    const int c2 = (lane & 15) * 2;      // channel pair
    if (n >= NN) return;
    const int beg = rows[n], end = rows[n + 1];
    float ax0 = 0.f, ay0 = 0.f, ax1 = 0.f, ay1 = 0.f;
    float ax2 = 0.f, ay2 = 0.f, ax3 = 0.f, ay3 = 0.f;
    int p = beg;
    for (; p + 16 <= end; p += 16) {
        const int e0 = csrc[p + g + 0];
        const int e1 = csrc[p + g + 4];
        const int e2 = csrc[p + g + 8];
        const int e3 = csrc[p + g + 12];
        const unsigned u0 = *(const unsigned*)&hw2s[(size_t)e0 * 32 + c2];
        const unsigned u1 = *(const unsigned*)&hw2s[(size_t)e1 * 32 + c2];
        const unsigned u2 = *(const unsigned*)&hw2s[(size_t)e2 * 32 + c2];
        const unsigned u3 = *(const unsigned*)&hw2s[(size_t)e3 * 32 + c2];
        ax0 += blo(u0); ay0 += bhi(u0);
        ax1 += blo(u1); ay1 += bhi(u1);
        ax2 += blo(u2); ay2 += bhi(u2);
        ax3 += blo(u3); ay3 += bhi(u3);
    }
    if (p + 8 <= end) {
        const int e0 = csrc[p + g + 0];
        const int e1 = csrc[p + g + 4];
        const unsigned u0 = *(const unsigned*)&hw2s[(size_t)e0 * 32 + c2];
        const unsigned u1 = *(const unsigned*)&hw2s[(size_t)e1 * 32 + c2];
        ax0 += blo(u0); ay0 += bhi(u0);
        ax1 += blo(u1); ay1 += bhi(u1);
        p += 8;
    }
    for (; p < end; p += 4) {
        if (g < end - p) {
            const int e = csrc[p + g];
            const unsigned u = *(const unsigned*)&hw2s[(size_t)e * 32 + c2];
            ax0 += blo(u); ay0 += bhi(u);
        }
    }
    float sx = (ax0 + ax1) + (ax2 + ax3);
    float sy = (ay0 + ay1) + (ay2 + ay3);
    sx += __shfl_xor(sx, 16); sx += __shfl_xor(sx, 32);
    sy += __shfl_xor(sy, 16); sy += __shfl_xor(sy, 32);
    if (lane < 16) {
        const float dn = dinv[n];
        const unsigned su = *(const unsigned*)&hw2s[(size_t)n * 32 + c2];
        const float2 bb = *(const float2*)&b2[c2];
        float2 r;
        r.x = fmaf(sx + blo(su), dn, bb.x);
        r.y = fmaf(sy + bhi(su), dn, bb.y);
        *(float2*)&h2[(size_t)n * 32 + c2] = r;
    }
}

// out[r][j] = sum_n O[r][n] * h2[n][j]
__global__ __launch_bounds__(256) void k_final(const float* __restrict__ O,
                                               const float* __restrict__ h2,
                                               float* __restrict__ out) {
    __shared__ float h2s[128][32];
    __shared__ float Os[64][128];
    const int t = threadIdx.x;
    const int n0 = blockIdx.x * 128;
    #pragma unroll
    for (int i = 0; i < 16; ++i) {
        const int idx = t + 256 * i;
        const int n = idx >> 5, j = idx & 31;
        const int node = n0 + n;
        h2s[n][j] = (node < NN) ? h2[(size_t)node * 32 + j] : 0.f;
    }
    #pragma unroll
    for (int i = 0; i < 32; ++i) {
        const int idx = t + 256 * i;
        const int r = idx >> 7, c = idx & 127;
        const int node = n0 + c;
        Os[r][c] = (node < NN) ? O[(size_t)r * NN + node] : 0.f;
    }
    __syncthreads();
    const int j = t & 31, k0 = (t >> 5) * 8;
    float acc[8];
    #pragma unroll
    for (int i = 0; i < 8; ++i) acc[i] = 0.f;
    for (int n = 0; n < 128; ++n) {
        const float hv = h2s[n][j];
        #pragma unroll
        for (int i = 0; i < 8; ++i) acc[i] = fmaf(Os[k0 + i][n], hv, acc[i]);
    }
    #pragma unroll
    for (int i = 0; i < 8; ++i) atomicAdd(&out[(k0 + i) * 32 + j], acc[i]);
}

extern "C" void kernel_launch(void* const* d_in, const int* in_sizes, int n_in,
                              void* d_out, int out_size, void* d_ws, size_t ws_size,
                              hipStream_t stream) {
    const float* x  = (const float*)d_in[0];
    const int*   ei = (const int*)d_in[1];
    const float* O  = (const float*)d_in[2];
    const float* W1 = (const float*)d_in[3];
    const float* b1 = (const float*)d_in[4];
    const float* W2 = (const float*)d_in[5];
    const float* b2 = (const float*)d_in[6];
    float* out = (float*)d_out;

    float* wsf = (float*)d_ws;
    unsigned short* h1s  = (unsigned short*)(wsf + OFF_H1);
    unsigned short* hw2s = (unsigned short*)(wsf + OFF_HW2);
    float*          h2   = wsf + OFF_H2;
    float* dinv  = wsf + OFF_DINV;
    int*   rows  = (int*)(wsf + OFF_ROWS);
    int*   gcnt  = (int*)(wsf + OFF_GCNT);
    int*   csrc  = (int*)(wsf + OFF_CSRC);
    unsigned* binned = (unsigned*)(wsf + OFF_BIN);
    unsigned short* w1t = (unsigned short*)(wsf + OFF_BIN);   // aliases dead binned
    unsigned* w2c = (unsigned*)((unsigned short*)(wsf + OFF_BIN) + 16384);

    hipMemsetAsync(gcnt, 0, NB * 4, stream);

    k_binA<<<256, 256, 0, stream>>>(ei, gcnt, binned);
    k_binB<<<NB, 256, 0, stream>>>(gcnt, binned, rows, dinv, csrc);

    k_wconv<<<17, 256, 0, stream>>>(W1, W2, w1t, w2c);
    k_gemm1<<<(NN + 63) / 64, 256, 0, stream>>>(x, w1t, dinv, h1s);
    k_gf1<<<(NN + 3) / 4, 256, 0, stream>>>(rows, csrc, dinv, h1s, b1, w2c, hw2s);
    k_gather2<<<(NN * 64 + 255) / 256, 256, 0, stream>>>(rows, csrc, dinv, hw2s, b2, h2);

    hipMemsetAsync(out, 0, (size_t)out_size * 4, stream);
    k_final<<<(NN + 127) / 128, 256, 0, stream>>>(O, h2, out);
}

// Round 18
// 180.339 us; speedup vs baseline: 1.0199x; 1.0199x over previous
//
#include <hip/hip_runtime.h>

#define NN 50000
#define NE 1600000
#define NB 782         // buckets = ceil(NN/64)
#define BSH 6          // bucket = dst >> 6
#define BCAP 2560      // per-bucket capacity: mean 2046 + ~11 sigma

// workspace layout (units of 4B)
#define OFF_H1    0          // bf16 [NN][128] = 3.2M u   (h1s = h1 * dinv)
#define OFF_HW2   9600000    // bf16 [NN][32]  = 0.8M u   (hw2s = hw2 * dinv)
#define OFF_H2    10400000   // f32  [NN][32]  = 1.6M u   (h2 = agg2+self+b2)
#define OFF_DINV  12000000   // [NN] f32
#define OFF_ROWS  12050000   // [NN+1] int
#define OFF_GCNT  12101000   // [NB] int
#define OFF_CSRC  12102000   // int[NE] = 1.6M u
#define OFF_BIN   13702000   // packed uint[NB*BCAP] = 2.0M u (dead after k_binB;
                             //  w1t bf16[128][128] + w2p uint[64*32] alias head)
// total: ~15.7M u * 4B = 63 MB

typedef __attribute__((ext_vector_type(8))) short bf16x8;
typedef __attribute__((ext_vector_type(8))) unsigned short u16x8;
typedef __attribute__((ext_vector_type(4))) float f32x4;

__device__ __forceinline__ unsigned short f2b(float f) {
    unsigned u = __float_as_uint(f);
    u += 0x7fffu + ((u >> 16) & 1u);
    return (unsigned short)(u >> 16);
}
__device__ __forceinline__ float b2f(unsigned short h) {
    return __uint_as_float((unsigned)h << 16);
}
__device__ __forceinline__ float blo(unsigned u) { return __uint_as_float(u << 16); }
__device__ __forceinline__ float bhi(unsigned u) { return __uint_as_float(u & 0xffff0000u); }

// Pass A: bin edges into 782 dst-buckets. Edge record packed to 4B:
// src in bits [15:0] (NN<65536), in-bucket dst (d&63) in bits [21:16].
__global__ __launch_bounds__(256) void k_binA(const int* __restrict__ ei,
                                              int* __restrict__ gcount,
                                              unsigned* __restrict__ binned) {
    __shared__ int hist[NB];
    const int t = threadIdx.x;
    for (int i = t; i < NB; i += 256) hist[i] = 0;
    __syncthreads();
    const int e0 = blockIdx.x * (NE / 256);      // 6250 edges/block, exact
    const int e1 = e0 + (NE / 256);
    for (int e = e0 + t; e < e1; e += 256)
        atomicAdd(&hist[ei[NE + e] >> BSH], 1);
    __syncthreads();
    for (int i = t; i < NB; i += 256) {
        const int v = hist[i];
        hist[i] = atomicAdd(&gcount[i], v);      // becomes global cursor
    }
    __syncthreads();
    for (int e = e0 + t; e < e1; e += 256) {
        const int s = ei[e], d = ei[NE + e];
        const int b = d >> BSH;
        const int pos = atomicAdd(&hist[b], 1);
        binned[(size_t)b * BCAP + pos] = (unsigned)s | ((unsigned)(d & 63) << 16);
    }
}

// Pass B: one block per 64-node bucket (782 blocks, ~2K edges each).
// obase computed per-block (reduce gcount[0..b-1]) -- k_base kernel folded in.
__global__ __launch_bounds__(256) void k_binB(const int* __restrict__ gcount,
                                              const unsigned* __restrict__ binned,
                                              int* __restrict__ rows,
                                              float* __restrict__ dinv,
                                              int* __restrict__ csrc) {
    __shared__ int deg[64];
    __shared__ int ofs[64];
    __shared__ int scn[64];
    __shared__ int red[256];
    const int b = blockIdx.x, t = threadIdx.x;
    const int n0 = b << BSH;
    const int nloc = (NN - n0 < 64) ? (NN - n0) : 64;
    const int cnt = gcount[b];
    // obase = exclusive prefix of gcount over buckets < b
    int part = 0;
    for (int i = t; i < b; i += 256) part += gcount[i];
    red[t] = part;
    if (t < 64) deg[t] = 0;
    __syncthreads();
    #pragma unroll
    for (int o = 128; o > 0; o >>= 1) {
        if (t < o) red[t] += red[t + o];
        __syncthreads();
    }
    const int obase = red[0];
    const unsigned* eb = binned + (size_t)b * BCAP;
    for (int i = t; i < cnt; i += 256) atomicAdd(&deg[eb[i] >> 16], 1);
    __syncthreads();
    if (t < 64) scn[t] = deg[t];
    __syncthreads();
    #pragma unroll
    for (int o = 1; o < 64; o <<= 1) {
        const int x = (t >= o && t < 64) ? scn[t - o] : 0;
        __syncthreads();
        if (t < 64) scn[t] += x;
        __syncthreads();
    }
    if (t < 64) {
        const int ep = scn[t] - deg[t];
        ofs[t] = ep;
        if (t < nloc) {
            rows[n0 + t] = obase + ep;
            dinv[n0 + t] = rsqrtf((float)deg[t] + 1.0f);
        }
    }
    if (b == NB - 1 && t == 0) rows[NN] = NE;
    __syncthreads();
    for (int i = t; i < cnt; i += 256) {
        const unsigned r = eb[i];
        const int local = atomicAdd(&ofs[r >> 16], 1);
        csrc[obase + local] = (int)(r & 0xffffu);
    }
}

// W1[k][c] f32 -> w1t[c][k] bf16; W2 f32 -> paired dwords
// w2p[k2*32+j] = bf16(W2[2k2][j]) | bf16(W2[2k2+1][j])<<16  (matches h1l dwords)
__global__ __launch_bounds__(256) void k_wconv(const float* __restrict__ W1,
                                               const float* __restrict__ W2,
                                               unsigned short* __restrict__ w1t,
                                               unsigned* __restrict__ w2p) {
    const int t = threadIdx.x;
    if (blockIdx.x < 16) {
        const int id = blockIdx.x * 1024 + t;
        #pragma unroll
        for (int i = 0; i < 4; ++i) {
            const int e = id + 256 * i;          // coalesced read of W1
            const int k = e >> 7, c = e & 127;
            w1t[c * 128 + k] = f2b(W1[e]);
        }
    } else {
        #pragma unroll
        for (int i = 0; i < 8; ++i) {
            const int e = t + 256 * i;           // 2048 paired entries
            const int k2 = e >> 5, j = e & 31;
            const unsigned lo = f2b(W2[(2 * k2) * 32 + j]);
            const unsigned hi = f2b(W2[(2 * k2 + 1) * 32 + j]);
            w2p[e] = lo | (hi << 16);
        }
    }
}

// MFMA GEMM: h1s[n][c] = dinv[n] * sum_k xT[n][k] * W1[k][c], bf16 out.
// LDS holds only the x tile; B-fragments stream from w1t in L2.
__global__ __launch_bounds__(256) void k_gemm1(const float* __restrict__ x,
                                               const unsigned short* __restrict__ w1t,
                                               const float* __restrict__ dinv,
                                               unsigned short* __restrict__ h1s) {
    __shared__ unsigned short lxs[64 * 136];   // x tile; reused as out tile
    const int t = threadIdx.x;
    const int gn0 = blockIdx.x * 64;
    {
        const int col = t & 63, kr = t >> 6;
        const int gn = gn0 + col;
        #pragma unroll
        for (int i = 0; i < 4; ++i) {
            const int k0 = kr * 32 + i * 8;
            u16x8 v;
            #pragma unroll
            for (int j = 0; j < 8; ++j) {
                const float xv = (gn < NN) ? x[(size_t)(k0 + j) * NN + gn] : 0.f;
                v[j] = f2b(xv);
            }
            *(u16x8*)&lxs[col * 136 + k0] = v;
        }
    }
    __syncthreads();
    const int w = t >> 6, l = t & 63;
    const int lr = l & 15, lg = l >> 4;      // lg = 0..3
    const unsigned short* pa = &lxs[(w * 16 + lr) * 136 + lg * 8];
    f32x4 acc[8];
    #pragma unroll
    for (int ct = 0; ct < 8; ++ct) acc[ct] = (f32x4){0.f, 0.f, 0.f, 0.f};
    #pragma unroll
    for (int ks = 0; ks < 4; ++ks) {
        const bf16x8 av = *(const bf16x8*)&pa[ks * 32];
        const unsigned short* pw = &w1t[lr * 128 + ks * 32 + lg * 8];
        const bf16x8 b0 = *(const bf16x8*)&pw[0 * 16 * 128];
        const bf16x8 b1 = *(const bf16x8*)&pw[1 * 16 * 128];
        const bf16x8 b2 = *(const bf16x8*)&pw[2 * 16 * 128];
        const bf16x8 b3 = *(const bf16x8*)&pw[3 * 16 * 128];
        const bf16x8 b4 = *(const bf16x8*)&pw[4 * 16 * 128];
        const bf16x8 b5 = *(const bf16x8*)&pw[5 * 16 * 128];
        const bf16x8 b6 = *(const bf16x8*)&pw[6 * 16 * 128];
        const bf16x8 b7 = *(const bf16x8*)&pw[7 * 16 * 128];
        acc[0] = __builtin_amdgcn_mfma_f32_16x16x32_bf16(av, b0, acc[0], 0, 0, 0);
        acc[1] = __builtin_amdgcn_mfma_f32_16x16x32_bf16(av, b1, acc[1], 0, 0, 0);
        acc[2] = __builtin_amdgcn_mfma_f32_16x16x32_bf16(av, b2, acc[2], 0, 0, 0);
        acc[3] = __builtin_amdgcn_mfma_f32_16x16x32_bf16(av, b3, acc[3], 0, 0, 0);
        acc[4] = __builtin_amdgcn_mfma_f32_16x16x32_bf16(av, b4, acc[4], 0, 0, 0);
        acc[5] = __builtin_amdgcn_mfma_f32_16x16x32_bf16(av, b5, acc[5], 0, 0, 0);
        acc[6] = __builtin_amdgcn_mfma_f32_16x16x32_bf16(av, b6, acc[6], 0, 0, 0);
        acc[7] = __builtin_amdgcn_mfma_f32_16x16x32_bf16(av, b7, acc[7], 0, 0, 0);
    }
    __syncthreads();                 // all lxs reads done; safe to overwrite
    // C/D layout: col = lane&15, row = (lane>>4)*4 + reg  [m89-verified]
    const int nl0 = w * 16 + lg * 4;
    const float4 dv = *(const float4*)&dinv[gn0 + nl0];   // may overread past NN
    const float dva[4] = {dv.x, dv.y, dv.z, dv.w};        // into rows[]: harmless
    #pragma unroll
    for (int ct = 0; ct < 8; ++ct) {
        const int c = ct * 16 + lr;
        #pragma unroll
        for (int r = 0; r < 4; ++r)
            lxs[(nl0 + r) * 136 + c] = f2b(acc[ct][r] * dva[r]);
    }
    __syncthreads();
    {
        const int row = t >> 2, cb = (t & 3) * 32;
        const int gn = gn0 + row;
        if (gn < NN) {
            #pragma unroll
            for (int i = 0; i < 4; ++i)
                *(u16x8*)&h1s[(size_t)gn * 128 + cb + i * 8] =
                    *(const u16x8*)&lxs[row * 136 + cb + i * 8];
        }
    }
}

// FUSED gather1+fuse1, wave-local epilogue: per wave -- 16-deep gather,
// self+bias+relu, write own 128-ch row to private LDS slot, read back
// IN-WAVE (no cross-wave barrier; only the start barrier after w2l staging).
// Dot split across lane-halves, combined via shfl_xor(32).
__global__ __launch_bounds__(256) void k_gf1(const int* __restrict__ rows,
                                             const int* __restrict__ csrc,
                                             const float* __restrict__ dinv,
                                             const unsigned short* __restrict__ h1s,
                                             const float* __restrict__ b1,
                                             const unsigned* __restrict__ w2p,
                                             unsigned short* __restrict__ hw2s) {
    __shared__ unsigned w2l[64 * 32];          // 8KB paired
    __shared__ unsigned h1l[4][64];            // 1KB (dword rows)
    const int t = threadIdx.x;
    ((f32x4*)w2l)[t]       = ((const f32x4*)w2p)[t];
    ((f32x4*)w2l)[t + 256] = ((const f32x4*)w2p)[t + 256];
    __syncthreads();                           // only barrier in kernel
    const int wid = t >> 6, lane = t & 63;
    const int n = __builtin_amdgcn_readfirstlane(blockIdx.x * 4 + wid);
    if (n >= NN) return;
    const int beg = rows[n], end = rows[n + 1];
    float ax0 = 0.f, ay0 = 0.f, ax1 = 0.f, ay1 = 0.f;
    float ax2 = 0.f, ay2 = 0.f, ax3 = 0.f, ay3 = 0.f;
    int p = beg;
    for (; p + 16 <= end; p += 16) {
        const int s0 = csrc[p + 0], s1 = csrc[p + 1], s2 = csrc[p + 2], s3 = csrc[p + 3];
        const int s4 = csrc[p + 4], s5 = csrc[p + 5], s6 = csrc[p + 6], s7 = csrc[p + 7];
        const int s8 = csrc[p + 8], s9 = csrc[p + 9], sa = csrc[p + 10], sb = csrc[p + 11];
        const int sc = csrc[p + 12], sd = csrc[p + 13], se = csrc[p + 14], sf = csrc[p + 15];
        const unsigned u0 = *(const unsigned*)&h1s[(size_t)s0 * 128 + lane * 2];
        const unsigned u1 = *(const unsigned*)&h1s[(size_t)s1 * 128 + lane * 2];
        const unsigned u2 = *(const unsigned*)&h1s[(size_t)s2 * 128 + lane * 2];
        const unsigned u3 = *(const unsigned*)&h1s[(size_t)s3 * 128 + lane * 2];
        const unsigned u4 = *(const unsigned*)&h1s[(size_t)s4 * 128 + lane * 2];
        const unsigned u5 = *(const unsigned*)&h1s[(size_t)s5 * 128 + lane * 2];
        const unsigned u6 = *(const unsigned*)&h1s[(size_t)s6 * 128 + lane * 2];
        const unsigned u7 = *(const unsigned*)&h1s[(size_t)s7 * 128 + lane * 2];
        const unsigned u8 = *(const unsigned*)&h1s[(size_t)s8 * 128 + lane * 2];
        const unsigned u9 = *(const unsigned*)&h1s[(size_t)s9 * 128 + lane * 2];
        const unsigned ua = *(const unsigned*)&h1s[(size_t)sa * 128 + lane * 2];
        const unsigned ub = *(const unsigned*)&h1s[(size_t)sb * 128 + lane * 2];
        const unsigned uc = *(const unsigned*)&h1s[(size_t)sc * 128 + lane * 2];
        const unsigned ud = *(const unsigned*)&h1s[(size_t)sd * 128 + lane * 2];
        const unsigned ue = *(const unsigned*)&h1s[(size_t)se * 128 + lane * 2];
        const unsigned uf = *(const unsigned*)&h1s[(size_t)sf * 128 + lane * 2];
        ax0 += blo(u0); ay0 += bhi(u0);
        ax1 += blo(u1); ay1 += bhi(u1);
        ax2 += blo(u2); ay2 += bhi(u2);
        ax3 += blo(u3); ay3 += bhi(u3);
        ax0 += blo(u4); ay0 += bhi(u4);
        ax1 += blo(u5); ay1 += bhi(u5);
        ax2 += blo(u6); ay2 += bhi(u6);
        ax3 += blo(u7); ay3 += bhi(u7);
        ax0 += blo(u8); ay0 += bhi(u8);
        ax1 += blo(u9); ay1 += bhi(u9);
        ax2 += blo(ua); ay2 += bhi(ua);
        ax3 += blo(ub); ay3 += bhi(ub);
        ax0 += blo(uc); ay0 += bhi(uc);
        ax1 += blo(ud); ay1 += bhi(ud);
        ax2 += blo(ue); ay2 += bhi(ue);
        ax3 += blo(uf); ay3 += bhi(uf);
    }
    for (; p + 4 <= end; p += 4) {
        const int s0 = csrc[p + 0], s1 = csrc[p + 1], s2 = csrc[p + 2], s3 = csrc[p + 3];
        const unsigned u0 = *(const unsigned*)&h1s[(size_t)s0 * 128 + lane * 2];
        const unsigned u1 = *(const unsigned*)&h1s[(size_t)s1 * 128 + lane * 2];
        const unsigned u2 = *(const unsigned*)&h1s[(size_t)s2 * 128 + lane * 2];
        const unsigned u3 = *(const unsigned*)&h1s[(size_t)s3 * 128 + lane * 2];
        ax0 += blo(u0); ay0 += bhi(u0);
        ax1 += blo(u1); ay1 += bhi(u1);
        ax2 += blo(u2); ay2 += bhi(u2);
        ax3 += blo(u3); ay3 += bhi(u3);
    }
    for (; p < end; ++p) {
        const int s = csrc[p];
        const unsigned u0 = *(const unsigned*)&h1s[(size_t)s * 128 + lane * 2];
        ax0 += blo(u0); ay0 += bhi(u0);
    }
    const float dn = dinv[n];
    const float sx = ((ax0 + ax1) + (ax2 + ax3)) * dn;
    const float sy = ((ay0 + ay1) + (ay2 + ay3)) * dn;
    // self-loop + bias + relu (h1s*dinv = h1/deg)
    const unsigned su = *(const unsigned*)&h1s[(size_t)n * 128 + lane * 2];
    const float2 bb = *(const float2*)&b1[lane * 2];
    const float vx = fmaxf(fmaf(blo(su), dn, sx) + bb.x, 0.f);
    const float vy = fmaxf(fmaf(bhi(su), dn, sy) + bb.y, 0.f);
    h1l[wid][lane] = (unsigned)f2b(vx) | ((unsigned)f2b(vy) << 16);
    // wave-local epilogue: same wave wrote h1l[wid] -- no barrier needed
    const int j = lane & 31, half = lane >> 5;
    const unsigned* hp = &h1l[wid][half * 32];
    const unsigned* wp = &w2l[half * 32 * 32 + j];
    float acc = 0.f;
    #pragma unroll 8
    for (int k2 = 0; k2 < 32; ++k2) {
        const unsigned hv = hp[k2];
        const unsigned wv = wp[k2 * 32];
        acc = fmaf(blo(hv), blo(wv), acc);
        acc = fmaf(bhi(hv), bhi(wv), acc);
    }
    acc += __shfl_xor(acc, 32);
    if (lane < 32) hw2s[(size_t)n * 32 + j] = f2b(acc * dn);
}

// one wave per dst node; 4 lane-groups x 16 channel-pairs: lane loads a
// 4B uint (2 channels) per edge -> 4 VMEM instrs cover 16 edges/lines.
// Reduce across groups via shfl_xor(16,32); fused epilogue:
// h2[n][j] = dinv*sum_e hw2s[src][j] + hw2s[n][j]*dinv + b2[j]
__global__ __launch_bounds__(256) void k_gather2(const int* __restrict__ rows,
                                                 const int* __restrict__ csrc,
                                                 const float* __restrict__ dinv,
                                                 const unsigned short* __restrict__ hw2s,
                                                 const float* __restrict__ b2,
                                                 float* __restrict__ h2) {
    const int n = __builtin_amdgcn_readfirstlane((blockIdx.x * 256 + threadIdx.x) >> 6);
    const int lane = threadIdx.x & 63;
    const int g = lane >> 4;             // edge slot 0..3
    const int c2 = (lane & 15) * 2;      // channel pair
    if (n >= NN) return;
    const int beg = rows[n], end = rows[n + 1];
    float ax0 = 0.f, ay0 = 0.f, ax1 = 0.f, ay1 = 0.f;
    float ax2 = 0.f, ay2 = 0.f, ax3 = 0.f, ay3 = 0.f;
    int p = beg;
    for (; p + 16 <= end; p += 16) {
        const int e0 = csrc[p + g + 0];
        const int e1 = csrc[p + g + 4];
        const int e2 = csrc[p + g + 8];
        const int e3 = csrc[p + g + 12];
        const unsigned u0 = *(const unsigned*)&hw2s[(size_t)e0 * 32 + c2];
        const unsigned u1 = *(const unsigned*)&hw2s[(size_t)e1 * 32 + c2];
        const unsigned u2 = *(const unsigned*)&hw2s[(size_t)e2 * 32 + c2];
        const unsigned u3 = *(const unsigned*)&hw2s[(size_t)e3 * 32 + c2];
        ax0 += blo(u0); ay0 += bhi(u0);
        ax1 += blo(u1); ay1 += bhi(u1);
        ax2 += blo(u2); ay2 += bhi(u2);
        ax3 += blo(u3); ay3 += bhi(u3);
    }
    if (p + 8 <= end) {
        const int e0 = csrc[p + g + 0];
        const int e1 = csrc[p + g + 4];
        const unsigned u0 = *(const unsigned*)&hw2s[(size_t)e0 * 32 + c2];
        const unsigned u1 = *(const unsigned*)&hw2s[(size_t)e1 * 32 + c2];
        ax0 += blo(u0); ay0 += bhi(u0);
        ax1 += blo(u1); ay1 += bhi(u1);
        p += 8;
    }
    for (; p < end; p += 4) {
        if (g < end - p) {
            const int e = csrc[p + g];
            const unsigned u = *(const unsigned*)&hw2s[(size_t)e * 32 + c2];
            ax0 += blo(u); ay0 += bhi(u);
        }
    }
    float sx = (ax0 + ax1) + (ax2 + ax3);
    float sy = (ay0 + ay1) + (ay2 + ay3);
    sx += __shfl_xor(sx, 16); sx += __shfl_xor(sx, 32);
    sy += __shfl_xor(sy, 16); sy += __shfl_xor(sy, 32);
    if (lane < 16) {
        const float dn = dinv[n];
        const unsigned su = *(const unsigned*)&hw2s[(size_t)n * 32 + c2];
        const float2 bb = *(const float2*)&b2[c2];
        float2 r;
        r.x = fmaf(sx + blo(su), dn, bb.x);
        r.y = fmaf(sy + bhi(su), dn, bb.y);
        *(float2*)&h2[(size_t)n * 32 + c2] = r;
    }
}

// out[r][j] = sum_n O[r][n] * h2[n][j]
__global__ __launch_bounds__(256) void k_final(const float* __restrict__ O,
                                               const float* __restrict__ h2,
                                               float* __restrict__ out) {
    __shared__ float h2s[128][32];
    __shared__ float Os[64][128];
    const int t = threadIdx.x;
    const int n0 = blockIdx.x * 128;
    #pragma unroll
    for (int i = 0; i < 16; ++i) {
        const int idx = t + 256 * i;
        const int n = idx >> 5, j = idx & 31;
        const int node = n0 + n;
        h2s[n][j] = (node < NN) ? h2[(size_t)node * 32 + j] : 0.f;
    }
    #pragma unroll
    for (int i = 0; i < 32; ++i) {
        const int idx = t + 256 * i;
        const int r = idx >> 7, c = idx & 127;
        const int node = n0 + c;
        Os[r][c] = (node < NN) ? O[(size_t)r * NN + node] : 0.f;
    }
    __syncthreads();
    const int j = t & 31, k0 = (t >> 5) * 8;
    float acc[8];
    #pragma unroll
    for (int i = 0; i < 8; ++i) acc[i] = 0.f;
    for (int n = 0; n < 128; ++n) {
        const float hv = h2s[n][j];
        #pragma unroll
        for (int i = 0; i < 8; ++i) acc[i] = fmaf(Os[k0 + i][n], hv, acc[i]);
    }
    #pragma unroll
    for (int i = 0; i < 8; ++i) atomicAdd(&out[(k0 + i) * 32 + j], acc[i]);
}

extern "C" void kernel_launch(void* const* d_in, const int* in_sizes, int n_in,
                              void* d_out, int out_size, void* d_ws, size_t ws_size,
                              hipStream_t stream) {
    const float* x  = (const float*)d_in[0];
    const int*   ei = (const int*)d_in[1];
    const float* O  = (const float*)d_in[2];
    const float* W1 = (const float*)d_in[3];
    const float* b1 = (const float*)d_in[4];
    const float* W2 = (const float*)d_in[5];
    const float* b2 = (const float*)d_in[6];
    float* out = (float*)d_out;

    float* wsf = (float*)d_ws;
    unsigned short* h1s  = (unsigned short*)(wsf + OFF_H1);
    unsigned short* hw2s = (unsigned short*)(wsf + OFF_HW2);
    float*          h2   = wsf + OFF_H2;
    float* dinv  = wsf + OFF_DINV;
    int*   rows  = (int*)(wsf + OFF_ROWS);
    int*   gcnt  = (int*)(wsf + OFF_GCNT);
    int*   csrc  = (int*)(wsf + OFF_CSRC);
    unsigned* binned = (unsigned*)(wsf + OFF_BIN);
    unsigned short* w1t = (unsigned short*)(wsf + OFF_BIN);   // aliases dead binned
    unsigned* w2p = (unsigned*)((unsigned short*)(wsf + OFF_BIN) + 16384);

    hipMemsetAsync(gcnt, 0, NB * 4, stream);

    k_binA<<<256, 256, 0, stream>>>(ei, gcnt, binned);
    k_binB<<<NB, 256, 0, stream>>>(gcnt, binned, rows, dinv, csrc);

    k_wconv<<<17, 256, 0, stream>>>(W1, W2, w1t, w2p);
    k_gemm1<<<(NN + 63) / 64, 256, 0, stream>>>(x, w1t, dinv, h1s);
    k_gf1<<<(NN + 3) / 4, 256, 0, stream>>>(rows, csrc, dinv, h1s, b1, w2p, hw2s);
    k_gather2<<<(NN * 64 + 255) / 256, 256, 0, stream>>>(rows, csrc, dinv, hw2s, b2, h2);

    hipMemsetAsync(out, 0, (size_t)out_size * 4, stream);
    k_final<<<(NN + 127) / 128, 256, 0, stream>>>(O, h2, out);
}